// Round 18
// baseline (5164.832 us; speedup 1.0000x reference)
//
#include <hip/hip_runtime.h>
#include <hip/hip_bf16.h>

typedef __hip_bfloat16 bf16;
typedef unsigned int uint32;

constexpr int NV=1024, TT=24, BB=8, CAP=80;

// ---- ws layout (float offsets) ---- node-major fields [b][n][C]
constexpr int O_CVAL = 0;               // 2048*80
constexpr int O_CIDX = 163840;          // 2048*80 ints
constexpr int O_CCNT = 327680;          // 2048 ints (padded-to-8 counts)
constexpr int O_LIWT = 329728;          // 66*64 f32 k-major
constexpr int O_GCWT = 333952;          // 64*64 u32 (bf16x2 pairs over k)
constexpr int O_LOWT = 342144;          // 64*64 u32
constexpr int O_FWT  = 350336;          // 165*64 u32
constexpr int O_UWT  = 371456;          // 165*64 u32
constexpr int O_CWT  = 392576;          // 165*64 u32
constexpr int O_H    = 413696;          // [b][n][64]
constexpr int O_T1   = 937984;          // xin ; XC aliases
constexpr int O_T3   = 1986560;         // U
constexpr int O_XH   = 2510848;         // [b][n][68] (66 used)
constexpr int O_Z1F  = 3067904;
constexpr int O_Z1B  = 3624960;
constexpr int O_PART = 4182016;         // [8][1024] float2 per-(b,n) partials
constexpr int O_RST  = 5296144;         // bf16 [24][8][1024][128]
constexpr int O_SST  = 17879056;        // bf16 [24][8][1024][64]
constexpr size_t WS_FLOATS = 24170512;
constexpr int O_XC = O_T1;
constexpr int O_U  = O_T3;

// ---- output layout (f32 elements) ----
constexpr int OFF_IMP  = 0;
constexpr int OFF_PRED = 196608;
constexpr int OFF_REPR = 393216;
constexpr int OFF_ST   = 25559040;

__device__ __forceinline__ bf16 f2b(float v){ return __float2bfloat16(v); }
__device__ __forceinline__ float b2f(bf16 v){ return __bfloat162float(v); }

__device__ __forceinline__ uint32 pkbf(float f){
  uint32 u = __float_as_uint(f);
  return (u + 0x7fffu + ((u>>16)&1u)) >> 16;
}
__device__ __forceinline__ uint32 pk2(float lo, float hi){ return pkbf(lo) | (pkbf(hi)<<16); }
__device__ __forceinline__ float unplo(uint32 u){ return __uint_as_float(u<<16); }
__device__ __forceinline__ float unphi(uint32 u){ return __uint_as_float(u & 0xffff0000u); }

// CSR build; rows zero-padded to a multiple of 8 entries (val=0 idx=0 contribute 0)
__global__ __launch_bounds__(64) void k_csr(const float* __restrict__ adj, float* __restrict__ ws){
  int row = blockIdx.x, lane = threadIdx.x;
  const float* a = adj + (size_t)row*NV;
  float* val = ws + O_CVAL + (size_t)row*CAP;
  int* idx = (int*)(ws+O_CIDX) + (size_t)row*CAP;
  int count = 0;
  for(int ch=0; ch<NV/64; ++ch){
    float v = a[ch*64+lane];
    unsigned long long m = __ballot(v != 0.f);
    int pre = __popcll(m & ((1ull<<lane)-1ull));
    if(v != 0.f){ int p = count+pre; if(p<CAP){ idx[p]=ch*64+lane; val[p]=v; } }
    count += __popcll(m);
  }
  if(count > CAP) count = CAP;
  int padded = (count + 7) & ~7;
  if(padded > CAP) padded = CAP;
  // zero-pad tail entries
  for(int p = count + lane; p < padded; p += 64){ idx[p] = 0; val[p] = 0.f; }
  if(lane==0) ((int*)(ws+O_CCNT))[row] = padded;
}

__global__ void k_prep_wt(const float* __restrict__ liW, const float* __restrict__ gcW,
    const float* __restrict__ loW, const float* __restrict__ fW,
    const float* __restrict__ uW, const float* __restrict__ cW, float* __restrict__ ws){
  int g = blockIdx.x*blockDim.x + threadIdx.x, G = gridDim.x*blockDim.x;
  for(int i=g;i<66*64;i+=G){ int k=i>>6, c=i&63; ws[O_LIWT+i]=liW[c*66+k]; }
  for(int i=g;i<64*64;i+=G){
    int p=i>>6, c=i&63;
    ((uint32*)(ws+O_GCWT))[i] = pk2(gcW[c*128+2*p], gcW[c*128+2*p+1]);
    ((uint32*)(ws+O_LOWT))[i] = pk2(loW[c*128+2*p], loW[c*128+2*p+1]);
  }
  for(int i=g;i<165*64;i+=G){
    int p=i>>6, c=i&63;
    ((uint32*)(ws+O_FWT))[i] = pk2(fW[c*330+2*p], fW[c*330+2*p+1]);
    ((uint32*)(ws+O_UWT))[i] = pk2(uW[c*330+2*p], uW[c*330+2*p+1]);
    ((uint32*)(ws+O_CWT))[i] = pk2(cW[c*330+2*p], cW[c*330+2*p+1]);
  }
}

__global__ __launch_bounds__(256) void k_h0(const float* __restrict__ h0, float* __restrict__ ws){
  int g = blockIdx.x*blockDim.x + threadIdx.x;
  if(g >= BB*NV*64) return;
  int c = g&63, n = (g>>6)&1023;
  ws[O_H + g] = h0[c*NV + n];
}

// kA: GroupNorm(t-1) finalize (half-wave per b) + states ; pred ; xin
__global__ __launch_bounds__(256) void kA(float* __restrict__ ws,
    const float* __restrict__ x, const float* __restrict__ mask,
    const float* __restrict__ fsW, const float* __restrict__ fsb,
    const float* __restrict__ lib, const float* __restrict__ gng,
    const float* __restrict__ gnb, float* __restrict__ dout, int t){
  __shared__ float hs[4][2][64];
  __shared__ float musd[8][2];
  int tid = threadIdx.x, wid = tid>>6, lane = tid&63;
  int n = blockIdx.x;
  if(t > 0){
    const float2* part = (const float2*)(ws+O_PART);
    int b = wid*2 + (lane>>5);
    int l5 = lane&31;
    float sx=0.f, sq=0.f;
    for(int i=l5;i<1024;i+=32){ float2 pp = part[b*1024+i]; sx+=pp.x; sq+=pp.y; }
    #pragma unroll
    for(int off=16;off;off>>=1){ sx+=__shfl_xor(sx,off,64); sq+=__shfl_xor(sq,off,64); }
    if(l5==0){ float mu=sx*(1.f/65536.f);
               musd[b][0]=mu; musd[b][1]=rsqrtf(sq*(1.f/65536.f)-mu*mu+1e-5f); }
    __syncthreads();
  }
  float gg = gng[lane], gb = gnb[lane];
  float x1v[2], xmv[2];
  #pragma unroll
  for(int j=0;j<2;++j){
    int b = wid*2+j;
    size_t col = (size_t)(b*NV+n);
    float h = ws[O_H + col*64 + lane];
    if(t > 0){
      h = (h - musd[b][0])*musd[b][1]*gg + gb;
      ws[O_H + col*64 + lane] = h;
      ((bf16*)(ws+O_SST))[(size_t)(t-1)*(BB*NV*64) + col*64 + lane] = f2b(h);
    }
    hs[wid][j][lane] = h;
    float pv = fsW[lane]*h;
    #pragma unroll
    for(int off=32; off; off>>=1) pv += __shfl_xor(pv, off, 64);
    float pred = pv + fsb[0];
    float xm = mask[col*TT + t];
    x1v[j] = (xm>0.f) ? x[col*TT + t] : pred;
    xmv[j] = xm;
    if(lane==0) dout[OFF_PRED + col*TT + t] = pred;
  }
  const float* Wt = ws + O_LIWT;
  float lb = lib[lane];
  float w0 = Wt[lane], w1 = Wt[64+lane];
  float a0 = lb + w0*x1v[0] + w1*xmv[0];
  float a1 = lb + w0*x1v[1] + w1*xmv[1];
  for(int j=0;j<64;++j){
    float w = Wt[(2+j)*64+lane];
    a0 += w*hs[wid][0][j];
    a1 += w*hs[wid][1][j];
  }
  ws[O_T1 + (size_t)((wid*2  )*NV+n)*64 + lane] = a0;
  ws[O_T1 + (size_t)((wid*2+1)*NV+n)*64 + lane] = a1;
}

// kB: prop64(T1) ; gc ; lo+PReLU+repr ; ro+imp ; XH  (bf16-packed gc/lo weights)
__global__ __launch_bounds__(256) void kB(float* __restrict__ ws,
    const float* __restrict__ x, const float* __restrict__ mask,
    const float* __restrict__ gcb, const float* __restrict__ lob,
    const float* __restrict__ prelu, const float* __restrict__ roW,
    const float* __restrict__ rob, float* __restrict__ dout, int t){
  __shared__ float pq[4][2][128];
  int tid=threadIdx.x, wid=tid>>6, lane=tid&63;
  int n = blockIdx.x;
  int b0 = wid*2, b1 = wid*2+1;
  const int* ccnt = (const int*)(ws+O_CCNT);
  float p0=0.f,p1=0.f,q0=0.f,q1=0.f;
  {
    int cn = ccnt[n];
    const int* id = (const int*)(ws+O_CIDX) + (size_t)n*CAP;
    const float* vl = ws + O_CVAL + (size_t)n*CAP;
    #pragma unroll 8
    for(int k=0;k<cn;++k){
      float a = vl[k]; int ix = id[k];
      p0 += a*ws[O_T1 + (size_t)(b0*NV+ix)*64 + lane];
      p1 += a*ws[O_T1 + (size_t)(b1*NV+ix)*64 + lane];
    }
  }
  {
    int cn = ccnt[NV+n];
    const int* id = (const int*)(ws+O_CIDX) + (size_t)(NV+n)*CAP;
    const float* vl = ws + O_CVAL + (size_t)(NV+n)*CAP;
    #pragma unroll 8
    for(int k=0;k<cn;++k){
      float a = vl[k]; int ix = id[k];
      q0 += a*ws[O_T1 + (size_t)(b0*NV+ix)*64 + lane];
      q1 += a*ws[O_T1 + (size_t)(b1*NV+ix)*64 + lane];
    }
  }
  pq[wid][0][lane]=p0; pq[wid][0][64+lane]=q0;
  pq[wid][1][lane]=p1; pq[wid][1][64+lane]=q1;
  const uint32* Gt = (const uint32*)(ws + O_GCWT);
  float g0 = gcb[lane], g1 = g0;
  for(int p=0;p<64;++p){
    uint32 u = Gt[p*64+lane];
    float wl = unplo(u), wh = unphi(u);
    g0 += wl*pq[wid][0][2*p] + wh*pq[wid][0][2*p+1];
    g1 += wl*pq[wid][1][2*p] + wh*pq[wid][1][2*p+1];
  }
  float hv0 = ws[O_H + (size_t)(b0*NV+n)*64 + lane];
  float hv1 = ws[O_H + (size_t)(b1*NV+n)*64 + lane];
  pq[wid][0][lane]=g0; pq[wid][0][64+lane]=hv0;
  pq[wid][1][lane]=g1; pq[wid][1][64+lane]=hv1;
  const uint32* Lt = (const uint32*)(ws + O_LOWT);
  float o0 = lob[lane], o1 = o0;
  for(int p=0;p<64;++p){
    uint32 u = Lt[p*64+lane];
    float wl = unplo(u), wh = unphi(u);
    o0 += wl*pq[wid][0][2*p] + wh*pq[wid][0][2*p+1];
    o1 += wl*pq[wid][1][2*p] + wh*pq[wid][1][2*p+1];
  }
  float a = prelu[0];
  float r0 = roW[lane], r1 = roW[64+lane], rb0 = rob[0];
  bf16* reprs = (bf16*)(ws + O_RST);
  #pragma unroll
  for(int j=0;j<2;++j){
    int b = wid*2+j;
    float ov = (j? o1 : o0);
    float hv = (j? hv1 : hv0);
    ov = (ov>=0.f)? ov : a*ov;
    size_t col = (size_t)(b*NV+n);
    size_t rbo = (((size_t)t*BB + b)*NV + n)*128;
    reprs[rbo + lane]      = f2b(ov);
    reprs[rbo + 64 + lane] = f2b(hv);
    float rv = r0*ov + r1*hv;
    #pragma unroll
    for(int off=32; off; off>>=1) rv += __shfl_xor(rv, off, 64);
    float xs2 = rv + rb0;
    float xm = mask[col*TT+t];
    float x2 = (xm>0.f) ? x[col*TT+t] : xs2;
    if(lane==0) dout[OFF_IMP + col*TT + t] = xs2;
    float* xh = ws + O_XH + col*68;
    xh[2+lane] = hv;
    if(lane==0){ xh[0]=x2; xh[1]=xm; }
  }
}

// prop66: dstF = fwd(srcF), dstB = bwd(srcB)
__global__ __launch_bounds__(256) void k_prop(float* __restrict__ ws, int srcF, int srcB,
    int dstF, int dstB){
  int tid=threadIdx.x, wid = tid>>6, lane = tid&63;
  int n = blockIdx.x;
  int b0 = wid*2, b1 = wid*2+1;
  const int* ccnt = (const int*)(ws+O_CCNT);
  bool hi = lane < 2;
  {
    int cn = ccnt[n];
    const int* id = (const int*)(ws+O_CIDX) + (size_t)n*CAP;
    const float* vl = ws + O_CVAL + (size_t)n*CAP;
    float a00=0.f,a01=0.f,a10=0.f,a11=0.f;
    #pragma unroll 8
    for(int k=0;k<cn;++k){
      float a = vl[k]; int ix = id[k];
      const float* r0 = ws + srcF + (size_t)(b0*NV + ix)*68;
      const float* r1 = ws + srcF + (size_t)(b1*NV + ix)*68;
      a00 += a*r0[lane]; if(hi) a01 += a*r0[64+lane];
      a10 += a*r1[lane]; if(hi) a11 += a*r1[64+lane];
    }
    float* d0 = ws + dstF + (size_t)(b0*NV+n)*68;
    float* d1 = ws + dstF + (size_t)(b1*NV+n)*68;
    d0[lane]=a00; if(hi) d0[64+lane]=a01;
    d1[lane]=a10; if(hi) d1[64+lane]=a11;
  }
  {
    int cn = ccnt[NV+n];
    const int* id = (const int*)(ws+O_CIDX) + (size_t)(NV+n)*CAP;
    const float* vl = ws + O_CVAL + (size_t)(NV+n)*CAP;
    float a00=0.f,a01=0.f,a10=0.f,a11=0.f;
    #pragma unroll 8
    for(int k=0;k<cn;++k){
      float a = vl[k]; int ix = id[k];
      const float* r0 = ws + srcB + (size_t)(b0*NV + ix)*68;
      const float* r1 = ws + srcB + (size_t)(b1*NV + ix)*68;
      a00 += a*r0[lane]; if(hi) a01 += a*r0[64+lane];
      a10 += a*r1[lane]; if(hi) a11 += a*r1[64+lane];
    }
    float* d0 = ws + dstB + (size_t)(b0*NV+n)*68;
    float* d1 = ws + dstB + (size_t)(b1*NV+n)*68;
    d0[lane]=a00; if(hi) d0[64+lane]=a01;
    d1[lane]=a10; if(hi) d1[64+lane]=a11;
  }
}

// kD: gates, 512 threads. wave-pair per batch-pair; halves split {stage+fwd | stage+bwd}
// gathers, then K-split the bf16-packed dot (pairs 0-82 / 83-164).
__global__ __launch_bounds__(512) void kD(float* __restrict__ ws,
    const float* __restrict__ fb, const float* __restrict__ ub){
  __shared__ float vec[4][2][332];
  __shared__ float acc[8][4][64];
  int tid=threadIdx.x, w=tid>>6, lane=tid&63;
  int pair=w>>1, half=w&1;
  int n = blockIdx.x;
  int b0 = pair*2, b1 = b0+1;
  size_t c0=(size_t)(b0*NV+n), c1=(size_t)(b1*NV+n);
  const int* ccnt = (const int*)(ws+O_CCNT);
  bool hi = lane < 2;
  if(half==0){
    const float* xh0 = ws + O_XH + c0*68;
    const float* xh1 = ws + O_XH + c1*68;
    const float* z1f0 = ws + O_Z1F + c0*68;
    const float* z1f1 = ws + O_Z1F + c1*68;
    vec[pair][0][lane]=xh0[lane];     if(hi) vec[pair][0][64+lane]=xh0[64+lane];
    vec[pair][1][lane]=xh1[lane];     if(hi) vec[pair][1][64+lane]=xh1[64+lane];
    vec[pair][0][66+lane]=z1f0[lane]; if(hi) vec[pair][0][130+lane]=z1f0[64+lane];
    vec[pair][1][66+lane]=z1f1[lane]; if(hi) vec[pair][1][130+lane]=z1f1[64+lane];
    int cn = ccnt[n];
    const int* id = (const int*)(ws+O_CIDX) + (size_t)n*CAP;
    const float* vl = ws + O_CVAL + (size_t)n*CAP;
    float a00=0.f,a01=0.f,a10=0.f,a11=0.f;
    #pragma unroll 8
    for(int k=0;k<cn;++k){
      float a = vl[k]; int ix = id[k];
      const float* r0 = ws + O_Z1F + (size_t)(b0*NV+ix)*68;
      const float* r1 = ws + O_Z1F + (size_t)(b1*NV+ix)*68;
      a00 += a*r0[lane]; if(hi) a01 += a*r0[64+lane];
      a10 += a*r1[lane]; if(hi) a11 += a*r1[64+lane];
    }
    vec[pair][0][132+lane]=a00; if(hi) vec[pair][0][196+lane]=a01;
    vec[pair][1][132+lane]=a10; if(hi) vec[pair][1][196+lane]=a11;
  } else {
    const float* z1b0 = ws + O_Z1B + c0*68;
    const float* z1b1 = ws + O_Z1B + c1*68;
    vec[pair][0][198+lane]=z1b0[lane]; if(hi) vec[pair][0][262+lane]=z1b0[64+lane];
    vec[pair][1][198+lane]=z1b1[lane]; if(hi) vec[pair][1][262+lane]=z1b1[64+lane];
    int cn = ccnt[NV+n];
    const int* id = (const int*)(ws+O_CIDX) + (size_t)(NV+n)*CAP;
    const float* vl = ws + O_CVAL + (size_t)(NV+n)*CAP;
    float a00=0.f,a01=0.f,a10=0.f,a11=0.f;
    #pragma unroll 8
    for(int k=0;k<cn;++k){
      float a = vl[k]; int ix = id[k];
      const float* r0 = ws + O_Z1B + (size_t)(b0*NV+ix)*68;
      const float* r1 = ws + O_Z1B + (size_t)(b1*NV+ix)*68;
      a00 += a*r0[lane]; if(hi) a01 += a*r0[64+lane];
      a10 += a*r1[lane]; if(hi) a11 += a*r1[64+lane];
    }
    vec[pair][0][264+lane]=a00; if(hi) vec[pair][0][328+lane]=a01;
    vec[pair][1][264+lane]=a10; if(hi) vec[pair][1][328+lane]=a11;
  }
  __syncthreads();
  const uint32* F2 = (const uint32*)(ws+O_FWT);
  const uint32* U2 = (const uint32*)(ws+O_UWT);
  int p0 = half? 83 : 0, p1 = half? 165 : 83;
  float ar0 = half? 0.f : fb[lane];
  float au0 = half? 0.f : ub[lane];
  float ar1 = ar0, au1 = au0;
  for(int p=p0;p<p1;++p){
    uint32 uf = F2[p*64+lane];
    uint32 uu = U2[p*64+lane];
    float fl=unplo(uf), fh=unphi(uf);
    float ul=unplo(uu), uh=unphi(uu);
    float v00 = vec[pair][0][2*p], v01 = vec[pair][0][2*p+1];
    float v10 = vec[pair][1][2*p], v11 = vec[pair][1][2*p+1];
    ar0 += fl*v00 + fh*v01;  ar1 += fl*v10 + fh*v11;
    au0 += ul*v00 + uh*v01;  au1 += ul*v10 + uh*v11;
  }
  acc[w][0][lane]=ar0; acc[w][1][lane]=ar1; acc[w][2][lane]=au0; acc[w][3][lane]=au1;
  __syncthreads();
  if(half==0){
    ar0 += acc[w+1][0][lane]; ar1 += acc[w+1][1][lane];
    au0 += acc[w+1][2][lane]; au1 += acc[w+1][3][lane];
    float r0 = 1.f/(1.f+expf(-ar0)), r1v = 1.f/(1.f+expf(-ar1));
    float u0 = 1.f/(1.f+expf(-au0)), u1v = 1.f/(1.f+expf(-au1));
    float hv0 = ws[O_H + c0*64 + lane];
    float hv1 = ws[O_H + c1*64 + lane];
    ws[O_U + c0*64 + lane] = u0;
    ws[O_U + c1*64 + lane] = u1v;
    float* xc0 = ws + O_XC + c0*68;
    float* xc1 = ws + O_XC + c1*68;
    xc0[2+lane] = r0*hv0; xc1[2+lane] = r1v*hv1;
    if(hi){ xc0[lane] = vec[pair][0][lane]; xc1[lane] = vec[pair][1][lane]; }
  }
}

// kF: candidate, 512 threads, bf16-packed dot; h_new ; stats partials
__global__ __launch_bounds__(512) void kF(float* __restrict__ ws, const float* __restrict__ cb){
  __shared__ float vec[4][2][332];
  __shared__ float acc[8][2][64];
  int tid=threadIdx.x, w=tid>>6, lane=tid&63;
  int pair=w>>1, half=w&1;
  int n = blockIdx.x;
  int b0 = pair*2, b1 = b0+1;
  size_t c0=(size_t)(b0*NV+n), c1=(size_t)(b1*NV+n);
  const int* ccnt = (const int*)(ws+O_CCNT);
  bool hi = lane < 2;
  if(half==0){
    const float* xc0 = ws + O_XC + c0*68;
    const float* xc1 = ws + O_XC + c1*68;
    const float* w1f0 = ws + O_Z1F + c0*68;
    const float* w1f1 = ws + O_Z1F + c1*68;
    vec[pair][0][lane]=xc0[lane];      if(hi) vec[pair][0][64+lane]=xc0[64+lane];
    vec[pair][1][lane]=xc1[lane];      if(hi) vec[pair][1][64+lane]=xc1[64+lane];
    vec[pair][0][66+lane]=w1f0[lane];  if(hi) vec[pair][0][130+lane]=w1f0[64+lane];
    vec[pair][1][66+lane]=w1f1[lane];  if(hi) vec[pair][1][130+lane]=w1f1[64+lane];
    int cn = ccnt[n];
    const int* id = (const int*)(ws+O_CIDX) + (size_t)n*CAP;
    const float* vl = ws + O_CVAL + (size_t)n*CAP;
    float a00=0.f,a01=0.f,a10=0.f,a11=0.f;
    #pragma unroll 8
    for(int k=0;k<cn;++k){
      float a = vl[k]; int ix = id[k];
      const float* r0 = ws + O_Z1F + (size_t)(b0*NV+ix)*68;
      const float* r1 = ws + O_Z1F + (size_t)(b1*NV+ix)*68;
      a00 += a*r0[lane]; if(hi) a01 += a*r0[64+lane];
      a10 += a*r1[lane]; if(hi) a11 += a*r1[64+lane];
    }
    vec[pair][0][132+lane]=a00; if(hi) vec[pair][0][196+lane]=a01;
    vec[pair][1][132+lane]=a10; if(hi) vec[pair][1][196+lane]=a11;
  } else {
    const float* w1b0 = ws + O_Z1B + c0*68;
    const float* w1b1 = ws + O_Z1B + c1*68;
    vec[pair][0][198+lane]=w1b0[lane]; if(hi) vec[pair][0][262+lane]=w1b0[64+lane];
    vec[pair][1][198+lane]=w1b1[lane]; if(hi) vec[pair][1][262+lane]=w1b1[64+lane];
    int cn = ccnt[NV+n];
    const int* id = (const int*)(ws+O_CIDX) + (size_t)(NV+n)*CAP;
    const float* vl = ws + O_CVAL + (size_t)(NV+n)*CAP;
    float a00=0.f,a01=0.f,a10=0.f,a11=0.f;
    #pragma unroll 8
    for(int k=0;k<cn;++k){
      float a = vl[k]; int ix = id[k];
      const float* r0 = ws + O_Z1B + (size_t)(b0*NV+ix)*68;
      const float* r1 = ws + O_Z1B + (size_t)(b1*NV+ix)*68;
      a00 += a*r0[lane]; if(hi) a01 += a*r0[64+lane];
      a10 += a*r1[lane]; if(hi) a11 += a*r1[64+lane];
    }
    vec[pair][0][264+lane]=a00; if(hi) vec[pair][0][328+lane]=a01;
    vec[pair][1][264+lane]=a10; if(hi) vec[pair][1][328+lane]=a11;
  }
  __syncthreads();
  const uint32* C2 = (const uint32*)(ws+O_CWT);
  int p0 = half? 83 : 0, p1 = half? 165 : 83;
  float ac0 = half? 0.f : cb[lane];
  float ac1 = ac0;
  for(int p=p0;p<p1;++p){
    uint32 uc = C2[p*64+lane];
    float cl=unplo(uc), ch=unphi(uc);
    ac0 += cl*vec[pair][0][2*p] + ch*vec[pair][0][2*p+1];
    ac1 += cl*vec[pair][1][2*p] + ch*vec[pair][1][2*p+1];
  }
  acc[w][0][lane]=ac0; acc[w][1][lane]=ac1;
  __syncthreads();
  if(half==0){
    ac0 += acc[w+1][0][lane];
    ac1 += acc[w+1][1][lane];
    #pragma unroll
    for(int j=0;j<2;++j){
      int b = b0+j;
      size_t col = (j? c1 : c0);
      float cd = tanhf(j? ac1 : ac0);
      float hv = ws[O_H + col*64 + lane];
      float u  = ws[O_U + col*64 + lane];
      float hn = u*hv + (1.f-u)*cd;
      ws[O_H + col*64 + lane] = hn;
      float s = hn, sq = hn*hn;
      #pragma unroll
      for(int off=32; off; off>>=1){ s += __shfl_xor(s, off, 64); sq += __shfl_xor(sq, off, 64); }
      if(lane==0) ((float2*)(ws+O_PART))[b*1024 + n] = make_float2(s, sq);
    }
  }
}

// final: normalize t=23 states from PART (half-wave per b reduce)
__global__ __launch_bounds__(256) void k_final(float* __restrict__ ws,
    const float* __restrict__ gng, const float* __restrict__ gnb){
  __shared__ float musd[8][2];
  int tid=threadIdx.x, wid=tid>>6, lane=tid&63;
  int n = blockIdx.x;
  const float2* part = (const float2*)(ws+O_PART);
  {
    int b = wid*2 + (lane>>5);
    int l5 = lane&31;
    float sx=0.f, sq=0.f;
    for(int i=l5;i<1024;i+=32){ float2 pp = part[b*1024+i]; sx+=pp.x; sq+=pp.y; }
    #pragma unroll
    for(int off=16;off;off>>=1){ sx+=__shfl_xor(sx,off,64); sq+=__shfl_xor(sq,off,64); }
    if(l5==0){ float mu=sx*(1.f/65536.f);
               musd[b][0]=mu; musd[b][1]=rsqrtf(sq*(1.f/65536.f)-mu*mu+1e-5f); }
    __syncthreads();
  }
  float gg=gng[lane], gb=gnb[lane];
  #pragma unroll
  for(int j=0;j<2;++j){
    int b = wid*2+j;
    size_t col = (size_t)(b*NV+n);
    float hn = ws[O_H + col*64 + lane];
    float h = (hn-musd[b][0])*musd[b][1]*gg + gb;
    ((bf16*)(ws+O_SST))[(size_t)23*(BB*NV*64) + col*64 + lane] = f2b(h);
  }
}

// transpose staging bf16 [t][b][n][CH] -> output f32 [b][CH][n][T]
__global__ __launch_bounds__(256) void k_transpose(const float* __restrict__ ws, float* __restrict__ dout,
                                                   int srcOff, int dstOff, int CH){
  __shared__ bf16 ld[32][16][26];
  int ct = CH/16;
  int per_b = 32*ct;
  int b = blockIdx.x / per_b;
  int r = blockIdx.x - b*per_b;
  int n0 = (r/ct)*32, ch0 = (r - (r/ct)*ct)*16;
  const bf16* src = (const bf16*)(ws + srcOff);
  for(int t=0;t<TT;++t){
    for(int i=threadIdx.x;i<512;i+=256){
      int cc=i&15, nn=i>>4;
      ld[nn][cc][t] = src[(((size_t)t*BB + b)*NV + n0+nn)*CH + ch0+cc];
    }
  }
  __syncthreads();
  for(int i=threadIdx.x;i<512;i+=256){
    int nn=i&31, cc=i>>5;
    size_t ob = ((size_t)(b*CH + ch0+cc)*NV + n0+nn)*TT;
    #pragma unroll
    for(int t=0;t<TT;++t) dout[dstOff + ob + t] = b2f(ld[nn][cc][t]);
  }
}

extern "C" void kernel_launch(void* const* d_in, const int* in_sizes, int n_in,
                              void* d_out, int out_size, void* d_ws, size_t ws_size,
                              hipStream_t stream){
  if(ws_size < WS_FLOATS * sizeof(float)) return;
  if(n_in < 23) return;

  float* ws = (float*)d_ws;
  float* out = (float*)d_out;

  const float* x    = (const float*)d_in[0];
  const float* mask = (const float*)d_in[1];
  const float* adj  = (const float*)d_in[2];
  const float* h0   = (const float*)d_in[3];
  const float* fsW  = (const float*)d_in[4];
  const float* fsb  = (const float*)d_in[5];
  const float* lib  = (const float*)d_in[7];
  const float* gcb  = (const float*)d_in[9];
  const float* lob  = (const float*)d_in[11];
  const float* roW  = (const float*)d_in[12];
  const float* rob  = (const float*)d_in[13];
  const float* prelu= (const float*)d_in[14];
  const float* fb   = (const float*)d_in[16];
  const float* ub   = (const float*)d_in[18];
  const float* cb   = (const float*)d_in[20];
  const float* gng  = (const float*)d_in[21];
  const float* gnb  = (const float*)d_in[22];

  k_csr    <<<dim3(2048), dim3(64),  0, stream>>>(adj, ws);
  k_prep_wt<<<dim3(64),   dim3(256), 0, stream>>>(
      (const float*)d_in[6], (const float*)d_in[8], (const float*)d_in[10],
      (const float*)d_in[15], (const float*)d_in[17], (const float*)d_in[19], ws);
  k_h0     <<<dim3(2048), dim3(256), 0, stream>>>(h0, ws);

  for(int t=0; t<TT; ++t){
    kA    <<<dim3(1024), dim3(256), 0, stream>>>(ws, x, mask, fsW, fsb, lib, gng, gnb, out, t);
    kB    <<<dim3(1024), dim3(256), 0, stream>>>(ws, x, mask, gcb, lob, prelu, roW, rob, out, t);
    k_prop<<<dim3(1024), dim3(256), 0, stream>>>(ws, O_XH, O_XH, O_Z1F, O_Z1B);
    kD    <<<dim3(1024), dim3(512), 0, stream>>>(ws, fb, ub);
    k_prop<<<dim3(1024), dim3(256), 0, stream>>>(ws, O_XC, O_XC, O_Z1F, O_Z1B);
    kF    <<<dim3(1024), dim3(512), 0, stream>>>(ws, cb);
  }
  k_final<<<dim3(1024), dim3(256), 0, stream>>>(ws, gng, gnb);

  k_transpose<<<dim3(2048), dim3(256), 0, stream>>>(ws, out, O_RST, OFF_REPR, 128);
  k_transpose<<<dim3(1024), dim3(256), 0, stream>>>(ws, out, O_SST, OFF_ST, 64);
}

// Round 19
// 5005.490 us; speedup vs baseline: 1.0318x; 1.0318x over previous
//
#include <hip/hip_runtime.h>
#include <hip/hip_bf16.h>

typedef __hip_bfloat16 bf16;
typedef unsigned int uint32;

constexpr int NV=1024, TT=24, BB=8, CAP=80;

// ---- ws layout (float offsets) ---- node-major fields [b][n][C]
constexpr int O_CVAL = 0;               // 2048*80
constexpr int O_CIDX = 163840;          // 2048*80 ints
constexpr int O_CCNT = 327680;          // 2048 ints
constexpr int O_LIWT = 329728;          // 66*64 f32 k-major
constexpr int O_GCWT = 333952;          // 64*64 u32 (bf16x2 pairs over k)
constexpr int O_LOWT = 342144;          // 64*64 u32
constexpr int O_FWT  = 350336;          // 165*64 u32
constexpr int O_UWT  = 371456;          // 165*64 u32
constexpr int O_CWT  = 392576;          // 165*64 u32
constexpr int O_H    = 413696;          // [b][n][64]
constexpr int O_T1   = 937984;          // xin ; XC aliases
constexpr int O_T3   = 1986560;         // U
constexpr int O_XH   = 2510848;         // [b][n][68] (66 used)
constexpr int O_Z1F  = 3067904;
constexpr int O_Z1B  = 3624960;
constexpr int O_PART = 4182016;         // [8][1024] float2 per-(b,n) partials
constexpr int O_RST  = 5296144;         // bf16 [24][8][1024][128]
constexpr int O_SST  = 17879056;        // bf16 [24][8][1024][64]
constexpr size_t WS_FLOATS = 24170512;
constexpr int O_XC = O_T1;
constexpr int O_U  = O_T3;

// ---- output layout (f32 elements) ----
constexpr int OFF_IMP  = 0;
constexpr int OFF_PRED = 196608;
constexpr int OFF_REPR = 393216;
constexpr int OFF_ST   = 25559040;

__device__ __forceinline__ bf16 f2b(float v){ return __float2bfloat16(v); }
__device__ __forceinline__ float b2f(bf16 v){ return __bfloat162float(v); }

__device__ __forceinline__ uint32 pkbf(float f){
  uint32 u = __float_as_uint(f);
  return (u + 0x7fffu + ((u>>16)&1u)) >> 16;
}
__device__ __forceinline__ uint32 pk2(float lo, float hi){ return pkbf(lo) | (pkbf(hi)<<16); }
__device__ __forceinline__ float unplo(uint32 u){ return __uint_as_float(u<<16); }
__device__ __forceinline__ float unphi(uint32 u){ return __uint_as_float(u & 0xffff0000u); }

__global__ __launch_bounds__(64) void k_csr(const float* __restrict__ adj, float* __restrict__ ws){
  int row = blockIdx.x, lane = threadIdx.x;
  const float* a = adj + (size_t)row*NV;
  float* val = ws + O_CVAL + (size_t)row*CAP;
  int* idx = (int*)(ws+O_CIDX) + (size_t)row*CAP;
  int count = 0;
  for(int ch=0; ch<NV/64; ++ch){
    float v = a[ch*64+lane];
    unsigned long long m = __ballot(v != 0.f);
    int pre = __popcll(m & ((1ull<<lane)-1ull));
    if(v != 0.f){ int p = count+pre; if(p<CAP){ idx[p]=ch*64+lane; val[p]=v; } }
    count += __popcll(m);
  }
  if(lane==0) ((int*)(ws+O_CCNT))[row] = count>CAP?CAP:count;
}

__global__ void k_prep_wt(const float* __restrict__ liW, const float* __restrict__ gcW,
    const float* __restrict__ loW, const float* __restrict__ fW,
    const float* __restrict__ uW, const float* __restrict__ cW, float* __restrict__ ws){
  int g = blockIdx.x*blockDim.x + threadIdx.x, G = gridDim.x*blockDim.x;
  for(int i=g;i<66*64;i+=G){ int k=i>>6, c=i&63; ws[O_LIWT+i]=liW[c*66+k]; }
  for(int i=g;i<64*64;i+=G){
    int p=i>>6, c=i&63;
    ((uint32*)(ws+O_GCWT))[i] = pk2(gcW[c*128+2*p], gcW[c*128+2*p+1]);
    ((uint32*)(ws+O_LOWT))[i] = pk2(loW[c*128+2*p], loW[c*128+2*p+1]);
  }
  for(int i=g;i<165*64;i+=G){
    int p=i>>6, c=i&63;
    ((uint32*)(ws+O_FWT))[i] = pk2(fW[c*330+2*p], fW[c*330+2*p+1]);
    ((uint32*)(ws+O_UWT))[i] = pk2(uW[c*330+2*p], uW[c*330+2*p+1]);
    ((uint32*)(ws+O_CWT))[i] = pk2(cW[c*330+2*p], cW[c*330+2*p+1]);
  }
}

__global__ __launch_bounds__(256) void k_h0(const float* __restrict__ h0, float* __restrict__ ws){
  int g = blockIdx.x*blockDim.x + threadIdx.x;
  if(g >= BB*NV*64) return;
  int c = g&63, n = (g>>6)&1023;
  ws[O_H + g] = h0[c*NV + n];
}

// kA: GroupNorm(t-1) finalize (half-wave per b) + states ; pred ; xin
__global__ __launch_bounds__(256) void kA(float* __restrict__ ws,
    const float* __restrict__ x, const float* __restrict__ mask,
    const float* __restrict__ fsW, const float* __restrict__ fsb,
    const float* __restrict__ lib, const float* __restrict__ gng,
    const float* __restrict__ gnb, float* __restrict__ dout, int t){
  __shared__ float hs[4][2][64];
  __shared__ float musd[8][2];
  int tid = threadIdx.x, wid = tid>>6, lane = tid&63;
  int n = blockIdx.x;
  if(t > 0){
    const float2* part = (const float2*)(ws+O_PART);
    int b = wid*2 + (lane>>5);
    int l5 = lane&31;
    float sx=0.f, sq=0.f;
    for(int i=l5;i<1024;i+=32){ float2 pp = part[b*1024+i]; sx+=pp.x; sq+=pp.y; }
    #pragma unroll
    for(int off=16;off;off>>=1){ sx+=__shfl_xor(sx,off,64); sq+=__shfl_xor(sq,off,64); }
    if(l5==0){ float mu=sx*(1.f/65536.f);
               musd[b][0]=mu; musd[b][1]=rsqrtf(sq*(1.f/65536.f)-mu*mu+1e-5f); }
    __syncthreads();
  }
  float gg = gng[lane], gb = gnb[lane];
  float x1v[2], xmv[2];
  #pragma unroll
  for(int j=0;j<2;++j){
    int b = wid*2+j;
    size_t col = (size_t)(b*NV+n);
    float h = ws[O_H + col*64 + lane];
    if(t > 0){
      h = (h - musd[b][0])*musd[b][1]*gg + gb;
      ws[O_H + col*64 + lane] = h;
      ((bf16*)(ws+O_SST))[(size_t)(t-1)*(BB*NV*64) + col*64 + lane] = f2b(h);
    }
    hs[wid][j][lane] = h;
    float pv = fsW[lane]*h;
    #pragma unroll
    for(int off=32; off; off>>=1) pv += __shfl_xor(pv, off, 64);
    float pred = pv + fsb[0];
    float xm = mask[col*TT + t];
    x1v[j] = (xm>0.f) ? x[col*TT + t] : pred;
    xmv[j] = xm;
    if(lane==0) dout[OFF_PRED + col*TT + t] = pred;
  }
  const float* Wt = ws + O_LIWT;
  float lb = lib[lane];
  float w0 = Wt[lane], w1 = Wt[64+lane];
  float a0 = lb + w0*x1v[0] + w1*xmv[0];
  float a1 = lb + w0*x1v[1] + w1*xmv[1];
  for(int j=0;j<64;++j){
    float w = Wt[(2+j)*64+lane];
    a0 += w*hs[wid][0][j];
    a1 += w*hs[wid][1][j];
  }
  ws[O_T1 + (size_t)((wid*2  )*NV+n)*64 + lane] = a0;
  ws[O_T1 + (size_t)((wid*2+1)*NV+n)*64 + lane] = a1;
}

// kB: prop64(T1) ; gc ; lo+PReLU+repr ; ro+imp ; XH  (bf16-packed gc/lo weights)
__global__ __launch_bounds__(256) void kB(float* __restrict__ ws,
    const float* __restrict__ x, const float* __restrict__ mask,
    const float* __restrict__ gcb, const float* __restrict__ lob,
    const float* __restrict__ prelu, const float* __restrict__ roW,
    const float* __restrict__ rob, float* __restrict__ dout, int t){
  __shared__ float pq[4][2][128];
  int tid=threadIdx.x, wid=tid>>6, lane=tid&63;
  int n = blockIdx.x;
  int b0 = wid*2, b1 = wid*2+1;
  const int* ccnt = (const int*)(ws+O_CCNT);
  float p0=0.f,p1=0.f,q0=0.f,q1=0.f;
  {
    int cn = ccnt[n];
    const int* id = (const int*)(ws+O_CIDX) + (size_t)n*CAP;
    const float* vl = ws + O_CVAL + (size_t)n*CAP;
    #pragma unroll 4
    for(int k=0;k<cn;++k){
      float a = vl[k]; int ix = id[k];
      p0 += a*ws[O_T1 + (size_t)(b0*NV+ix)*64 + lane];
      p1 += a*ws[O_T1 + (size_t)(b1*NV+ix)*64 + lane];
    }
  }
  {
    int cn = ccnt[NV+n];
    const int* id = (const int*)(ws+O_CIDX) + (size_t)(NV+n)*CAP;
    const float* vl = ws + O_CVAL + (size_t)(NV+n)*CAP;
    #pragma unroll 4
    for(int k=0;k<cn;++k){
      float a = vl[k]; int ix = id[k];
      q0 += a*ws[O_T1 + (size_t)(b0*NV+ix)*64 + lane];
      q1 += a*ws[O_T1 + (size_t)(b1*NV+ix)*64 + lane];
    }
  }
  pq[wid][0][lane]=p0; pq[wid][0][64+lane]=q0;
  pq[wid][1][lane]=p1; pq[wid][1][64+lane]=q1;
  const uint32* Gt = (const uint32*)(ws + O_GCWT);
  float g0 = gcb[lane], g1 = g0;
  for(int p=0;p<64;++p){
    uint32 u = Gt[p*64+lane];
    float wl = unplo(u), wh = unphi(u);
    g0 += wl*pq[wid][0][2*p] + wh*pq[wid][0][2*p+1];
    g1 += wl*pq[wid][1][2*p] + wh*pq[wid][1][2*p+1];
  }
  float hv0 = ws[O_H + (size_t)(b0*NV+n)*64 + lane];
  float hv1 = ws[O_H + (size_t)(b1*NV+n)*64 + lane];
  pq[wid][0][lane]=g0; pq[wid][0][64+lane]=hv0;
  pq[wid][1][lane]=g1; pq[wid][1][64+lane]=hv1;
  const uint32* Lt = (const uint32*)(ws + O_LOWT);
  float o0 = lob[lane], o1 = o0;
  for(int p=0;p<64;++p){
    uint32 u = Lt[p*64+lane];
    float wl = unplo(u), wh = unphi(u);
    o0 += wl*pq[wid][0][2*p] + wh*pq[wid][0][2*p+1];
    o1 += wl*pq[wid][1][2*p] + wh*pq[wid][1][2*p+1];
  }
  float a = prelu[0];
  float r0 = roW[lane], r1 = roW[64+lane], rb0 = rob[0];
  bf16* reprs = (bf16*)(ws + O_RST);
  #pragma unroll
  for(int j=0;j<2;++j){
    int b = wid*2+j;
    float ov = (j? o1 : o0);
    float hv = (j? hv1 : hv0);
    ov = (ov>=0.f)? ov : a*ov;
    size_t col = (size_t)(b*NV+n);
    size_t rbo = (((size_t)t*BB + b)*NV + n)*128;
    reprs[rbo + lane]      = f2b(ov);
    reprs[rbo + 64 + lane] = f2b(hv);
    float rv = r0*ov + r1*hv;
    #pragma unroll
    for(int off=32; off; off>>=1) rv += __shfl_xor(rv, off, 64);
    float xs2 = rv + rb0;
    float xm = mask[col*TT+t];
    float x2 = (xm>0.f) ? x[col*TT+t] : xs2;
    if(lane==0) dout[OFF_IMP + col*TT + t] = xs2;
    float* xh = ws + O_XH + col*68;
    xh[2+lane] = hv;
    if(lane==0){ xh[0]=x2; xh[1]=xm; }
  }
}

// prop66: dstF = fwd(srcF), dstB = bwd(srcB)
__global__ __launch_bounds__(256) void k_prop(float* __restrict__ ws, int srcF, int srcB,
    int dstF, int dstB){
  int tid=threadIdx.x, wid = tid>>6, lane = tid&63;
  int n = blockIdx.x;
  int b0 = wid*2, b1 = wid*2+1;
  const int* ccnt = (const int*)(ws+O_CCNT);
  bool hi = lane < 2;
  {
    int cn = ccnt[n];
    const int* id = (const int*)(ws+O_CIDX) + (size_t)n*CAP;
    const float* vl = ws + O_CVAL + (size_t)n*CAP;
    float a00=0.f,a01=0.f,a10=0.f,a11=0.f;
    #pragma unroll 4
    for(int k=0;k<cn;++k){
      float a = vl[k]; int ix = id[k];
      const float* r0 = ws + srcF + (size_t)(b0*NV + ix)*68;
      const float* r1 = ws + srcF + (size_t)(b1*NV + ix)*68;
      a00 += a*r0[lane]; if(hi) a01 += a*r0[64+lane];
      a10 += a*r1[lane]; if(hi) a11 += a*r1[64+lane];
    }
    float* d0 = ws + dstF + (size_t)(b0*NV+n)*68;
    float* d1 = ws + dstF + (size_t)(b1*NV+n)*68;
    d0[lane]=a00; if(hi) d0[64+lane]=a01;
    d1[lane]=a10; if(hi) d1[64+lane]=a11;
  }
  {
    int cn = ccnt[NV+n];
    const int* id = (const int*)(ws+O_CIDX) + (size_t)(NV+n)*CAP;
    const float* vl = ws + O_CVAL + (size_t)(NV+n)*CAP;
    float a00=0.f,a01=0.f,a10=0.f,a11=0.f;
    #pragma unroll 4
    for(int k=0;k<cn;++k){
      float a = vl[k]; int ix = id[k];
      const float* r0 = ws + srcB + (size_t)(b0*NV + ix)*68;
      const float* r1 = ws + srcB + (size_t)(b1*NV + ix)*68;
      a00 += a*r0[lane]; if(hi) a01 += a*r0[64+lane];
      a10 += a*r1[lane]; if(hi) a11 += a*r1[64+lane];
    }
    float* d0 = ws + dstB + (size_t)(b0*NV+n)*68;
    float* d1 = ws + dstB + (size_t)(b1*NV+n)*68;
    d0[lane]=a00; if(hi) d0[64+lane]=a01;
    d1[lane]=a10; if(hi) d1[64+lane]=a11;
  }
}

// kD: gates, 512 threads. wave-pair per batch-pair; halves split {stage+fwd | stage+bwd}
// gathers, then K-split the bf16-packed dot (pairs 0-82 / 83-164).
__global__ __launch_bounds__(512) void kD(float* __restrict__ ws,
    const float* __restrict__ fb, const float* __restrict__ ub){
  __shared__ float vec[4][2][332];
  __shared__ float acc[8][4][64];
  int tid=threadIdx.x, w=tid>>6, lane=tid&63;
  int pair=w>>1, half=w&1;
  int n = blockIdx.x;
  int b0 = pair*2, b1 = b0+1;
  size_t c0=(size_t)(b0*NV+n), c1=(size_t)(b1*NV+n);
  const int* ccnt = (const int*)(ws+O_CCNT);
  bool hi = lane < 2;
  if(half==0){
    const float* xh0 = ws + O_XH + c0*68;
    const float* xh1 = ws + O_XH + c1*68;
    const float* z1f0 = ws + O_Z1F + c0*68;
    const float* z1f1 = ws + O_Z1F + c1*68;
    vec[pair][0][lane]=xh0[lane];     if(hi) vec[pair][0][64+lane]=xh0[64+lane];
    vec[pair][1][lane]=xh1[lane];     if(hi) vec[pair][1][64+lane]=xh1[64+lane];
    vec[pair][0][66+lane]=z1f0[lane]; if(hi) vec[pair][0][130+lane]=z1f0[64+lane];
    vec[pair][1][66+lane]=z1f1[lane]; if(hi) vec[pair][1][130+lane]=z1f1[64+lane];
    int cn = ccnt[n];
    const int* id = (const int*)(ws+O_CIDX) + (size_t)n*CAP;
    const float* vl = ws + O_CVAL + (size_t)n*CAP;
    float a00=0.f,a01=0.f,a10=0.f,a11=0.f;
    #pragma unroll 4
    for(int k=0;k<cn;++k){
      float a = vl[k]; int ix = id[k];
      const float* r0 = ws + O_Z1F + (size_t)(b0*NV+ix)*68;
      const float* r1 = ws + O_Z1F + (size_t)(b1*NV+ix)*68;
      a00 += a*r0[lane]; if(hi) a01 += a*r0[64+lane];
      a10 += a*r1[lane]; if(hi) a11 += a*r1[64+lane];
    }
    vec[pair][0][132+lane]=a00; if(hi) vec[pair][0][196+lane]=a01;
    vec[pair][1][132+lane]=a10; if(hi) vec[pair][1][196+lane]=a11;
  } else {
    const float* z1b0 = ws + O_Z1B + c0*68;
    const float* z1b1 = ws + O_Z1B + c1*68;
    vec[pair][0][198+lane]=z1b0[lane]; if(hi) vec[pair][0][262+lane]=z1b0[64+lane];
    vec[pair][1][198+lane]=z1b1[lane]; if(hi) vec[pair][1][262+lane]=z1b1[64+lane];
    int cn = ccnt[NV+n];
    const int* id = (const int*)(ws+O_CIDX) + (size_t)(NV+n)*CAP;
    const float* vl = ws + O_CVAL + (size_t)(NV+n)*CAP;
    float a00=0.f,a01=0.f,a10=0.f,a11=0.f;
    #pragma unroll 4
    for(int k=0;k<cn;++k){
      float a = vl[k]; int ix = id[k];
      const float* r0 = ws + O_Z1B + (size_t)(b0*NV+ix)*68;
      const float* r1 = ws + O_Z1B + (size_t)(b1*NV+ix)*68;
      a00 += a*r0[lane]; if(hi) a01 += a*r0[64+lane];
      a10 += a*r1[lane]; if(hi) a11 += a*r1[64+lane];
    }
    vec[pair][0][264+lane]=a00; if(hi) vec[pair][0][328+lane]=a01;
    vec[pair][1][264+lane]=a10; if(hi) vec[pair][1][328+lane]=a11;
  }
  __syncthreads();
  const uint32* F2 = (const uint32*)(ws+O_FWT);
  const uint32* U2 = (const uint32*)(ws+O_UWT);
  int p0 = half? 83 : 0, p1 = half? 165 : 83;
  float ar0 = half? 0.f : fb[lane];
  float au0 = half? 0.f : ub[lane];
  float ar1 = ar0, au1 = au0;
  for(int p=p0;p<p1;++p){
    uint32 uf = F2[p*64+lane];
    uint32 uu = U2[p*64+lane];
    float fl=unplo(uf), fh=unphi(uf);
    float ul=unplo(uu), uh=unphi(uu);
    float v00 = vec[pair][0][2*p], v01 = vec[pair][0][2*p+1];
    float v10 = vec[pair][1][2*p], v11 = vec[pair][1][2*p+1];
    ar0 += fl*v00 + fh*v01;  ar1 += fl*v10 + fh*v11;
    au0 += ul*v00 + uh*v01;  au1 += ul*v10 + uh*v11;
  }
  acc[w][0][lane]=ar0; acc[w][1][lane]=ar1; acc[w][2][lane]=au0; acc[w][3][lane]=au1;
  __syncthreads();
  if(half==0){
    ar0 += acc[w+1][0][lane]; ar1 += acc[w+1][1][lane];
    au0 += acc[w+1][2][lane]; au1 += acc[w+1][3][lane];
    float r0 = 1.f/(1.f+expf(-ar0)), r1v = 1.f/(1.f+expf(-ar1));
    float u0 = 1.f/(1.f+expf(-au0)), u1v = 1.f/(1.f+expf(-au1));
    float hv0 = ws[O_H + c0*64 + lane];
    float hv1 = ws[O_H + c1*64 + lane];
    ws[O_U + c0*64 + lane] = u0;
    ws[O_U + c1*64 + lane] = u1v;
    float* xc0 = ws + O_XC + c0*68;
    float* xc1 = ws + O_XC + c1*68;
    xc0[2+lane] = r0*hv0; xc1[2+lane] = r1v*hv1;
    if(hi){ xc0[lane] = vec[pair][0][lane]; xc1[lane] = vec[pair][1][lane]; }
  }
}

// kF: candidate, 512 threads, bf16-packed dot; h_new ; stats partials
__global__ __launch_bounds__(512) void kF(float* __restrict__ ws, const float* __restrict__ cb){
  __shared__ float vec[4][2][332];
  __shared__ float acc[8][2][64];
  int tid=threadIdx.x, w=tid>>6, lane=tid&63;
  int pair=w>>1, half=w&1;
  int n = blockIdx.x;
  int b0 = pair*2, b1 = b0+1;
  size_t c0=(size_t)(b0*NV+n), c1=(size_t)(b1*NV+n);
  const int* ccnt = (const int*)(ws+O_CCNT);
  bool hi = lane < 2;
  if(half==0){
    const float* xc0 = ws + O_XC + c0*68;
    const float* xc1 = ws + O_XC + c1*68;
    const float* w1f0 = ws + O_Z1F + c0*68;
    const float* w1f1 = ws + O_Z1F + c1*68;
    vec[pair][0][lane]=xc0[lane];      if(hi) vec[pair][0][64+lane]=xc0[64+lane];
    vec[pair][1][lane]=xc1[lane];      if(hi) vec[pair][1][64+lane]=xc1[64+lane];
    vec[pair][0][66+lane]=w1f0[lane];  if(hi) vec[pair][0][130+lane]=w1f0[64+lane];
    vec[pair][1][66+lane]=w1f1[lane];  if(hi) vec[pair][1][130+lane]=w1f1[64+lane];
    int cn = ccnt[n];
    const int* id = (const int*)(ws+O_CIDX) + (size_t)n*CAP;
    const float* vl = ws + O_CVAL + (size_t)n*CAP;
    float a00=0.f,a01=0.f,a10=0.f,a11=0.f;
    #pragma unroll 4
    for(int k=0;k<cn;++k){
      float a = vl[k]; int ix = id[k];
      const float* r0 = ws + O_Z1F + (size_t)(b0*NV+ix)*68;
      const float* r1 = ws + O_Z1F + (size_t)(b1*NV+ix)*68;
      a00 += a*r0[lane]; if(hi) a01 += a*r0[64+lane];
      a10 += a*r1[lane]; if(hi) a11 += a*r1[64+lane];
    }
    vec[pair][0][132+lane]=a00; if(hi) vec[pair][0][196+lane]=a01;
    vec[pair][1][132+lane]=a10; if(hi) vec[pair][1][196+lane]=a11;
  } else {
    const float* w1b0 = ws + O_Z1B + c0*68;
    const float* w1b1 = ws + O_Z1B + c1*68;
    vec[pair][0][198+lane]=w1b0[lane]; if(hi) vec[pair][0][262+lane]=w1b0[64+lane];
    vec[pair][1][198+lane]=w1b1[lane]; if(hi) vec[pair][1][262+lane]=w1b1[64+lane];
    int cn = ccnt[NV+n];
    const int* id = (const int*)(ws+O_CIDX) + (size_t)(NV+n)*CAP;
    const float* vl = ws + O_CVAL + (size_t)(NV+n)*CAP;
    float a00=0.f,a01=0.f,a10=0.f,a11=0.f;
    #pragma unroll 4
    for(int k=0;k<cn;++k){
      float a = vl[k]; int ix = id[k];
      const float* r0 = ws + O_Z1B + (size_t)(b0*NV+ix)*68;
      const float* r1 = ws + O_Z1B + (size_t)(b1*NV+ix)*68;
      a00 += a*r0[lane]; if(hi) a01 += a*r0[64+lane];
      a10 += a*r1[lane]; if(hi) a11 += a*r1[64+lane];
    }
    vec[pair][0][264+lane]=a00; if(hi) vec[pair][0][328+lane]=a01;
    vec[pair][1][264+lane]=a10; if(hi) vec[pair][1][328+lane]=a11;
  }
  __syncthreads();
  const uint32* C2 = (const uint32*)(ws+O_CWT);
  int p0 = half? 83 : 0, p1 = half? 165 : 83;
  float ac0 = half? 0.f : cb[lane];
  float ac1 = ac0;
  for(int p=p0;p<p1;++p){
    uint32 uc = C2[p*64+lane];
    float cl=unplo(uc), ch=unphi(uc);
    ac0 += cl*vec[pair][0][2*p] + ch*vec[pair][0][2*p+1];
    ac1 += cl*vec[pair][1][2*p] + ch*vec[pair][1][2*p+1];
  }
  acc[w][0][lane]=ac0; acc[w][1][lane]=ac1;
  __syncthreads();
  if(half==0){
    ac0 += acc[w+1][0][lane];
    ac1 += acc[w+1][1][lane];
    #pragma unroll
    for(int j=0;j<2;++j){
      int b = b0+j;
      size_t col = (j? c1 : c0);
      float cd = tanhf(j? ac1 : ac0);
      float hv = ws[O_H + col*64 + lane];
      float u  = ws[O_U + col*64 + lane];
      float hn = u*hv + (1.f-u)*cd;
      ws[O_H + col*64 + lane] = hn;
      float s = hn, sq = hn*hn;
      #pragma unroll
      for(int off=32; off; off>>=1){ s += __shfl_xor(s, off, 64); sq += __shfl_xor(sq, off, 64); }
      if(lane==0) ((float2*)(ws+O_PART))[b*1024 + n] = make_float2(s, sq);
    }
  }
}

// final: normalize t=23 states from PART (half-wave per b reduce)
__global__ __launch_bounds__(256) void k_final(float* __restrict__ ws,
    const float* __restrict__ gng, const float* __restrict__ gnb){
  __shared__ float musd[8][2];
  int tid=threadIdx.x, wid=tid>>6, lane=tid&63;
  int n = blockIdx.x;
  const float2* part = (const float2*)(ws+O_PART);
  {
    int b = wid*2 + (lane>>5);
    int l5 = lane&31;
    float sx=0.f, sq=0.f;
    for(int i=l5;i<1024;i+=32){ float2 pp = part[b*1024+i]; sx+=pp.x; sq+=pp.y; }
    #pragma unroll
    for(int off=16;off;off>>=1){ sx+=__shfl_xor(sx,off,64); sq+=__shfl_xor(sq,off,64); }
    if(l5==0){ float mu=sx*(1.f/65536.f);
               musd[b][0]=mu; musd[b][1]=rsqrtf(sq*(1.f/65536.f)-mu*mu+1e-5f); }
    __syncthreads();
  }
  float gg=gng[lane], gb=gnb[lane];
  #pragma unroll
  for(int j=0;j<2;++j){
    int b = wid*2+j;
    size_t col = (size_t)(b*NV+n);
    float hn = ws[O_H + col*64 + lane];
    float h = (hn-musd[b][0])*musd[b][1]*gg + gb;
    ((bf16*)(ws+O_SST))[(size_t)23*(BB*NV*64) + col*64 + lane] = f2b(h);
  }
}

// transpose staging bf16 [t][b][n][CH] -> output f32 [b][CH][n][T]
__global__ __launch_bounds__(256) void k_transpose(const float* __restrict__ ws, float* __restrict__ dout,
                                                   int srcOff, int dstOff, int CH){
  __shared__ bf16 ld[32][16][26];
  int ct = CH/16;
  int per_b = 32*ct;
  int b = blockIdx.x / per_b;
  int r = blockIdx.x - b*per_b;
  int n0 = (r/ct)*32, ch0 = (r - (r/ct)*ct)*16;
  const bf16* src = (const bf16*)(ws + srcOff);
  for(int t=0;t<TT;++t){
    for(int i=threadIdx.x;i<512;i+=256){
      int cc=i&15, nn=i>>4;
      ld[nn][cc][t] = src[(((size_t)t*BB + b)*NV + n0+nn)*CH + ch0+cc];
    }
  }
  __syncthreads();
  for(int i=threadIdx.x;i<512;i+=256){
    int nn=i&31, cc=i>>5;
    size_t ob = ((size_t)(b*CH + ch0+cc)*NV + n0+nn)*TT;
    #pragma unroll
    for(int t=0;t<TT;++t) dout[dstOff + ob + t] = b2f(ld[nn][cc][t]);
  }
}

extern "C" void kernel_launch(void* const* d_in, const int* in_sizes, int n_in,
                              void* d_out, int out_size, void* d_ws, size_t ws_size,
                              hipStream_t stream){
  if(ws_size < WS_FLOATS * sizeof(float)) return;
  if(n_in < 23) return;

  float* ws = (float*)d_ws;
  float* out = (float*)d_out;

  const float* x    = (const float*)d_in[0];
  const float* mask = (const float*)d_in[1];
  const float* adj  = (const float*)d_in[2];
  const float* h0   = (const float*)d_in[3];
  const float* fsW  = (const float*)d_in[4];
  const float* fsb  = (const float*)d_in[5];
  const float* lib  = (const float*)d_in[7];
  const float* gcb  = (const float*)d_in[9];
  const float* lob  = (const float*)d_in[11];
  const float* roW  = (const float*)d_in[12];
  const float* rob  = (const float*)d_in[13];
  const float* prelu= (const float*)d_in[14];
  const float* fb   = (const float*)d_in[16];
  const float* ub   = (const float*)d_in[18];
  const float* cb   = (const float*)d_in[20];
  const float* gng  = (const float*)d_in[21];
  const float* gnb  = (const float*)d_in[22];

  k_csr    <<<dim3(2048), dim3(64),  0, stream>>>(adj, ws);
  k_prep_wt<<<dim3(64),   dim3(256), 0, stream>>>(
      (const float*)d_in[6], (const float*)d_in[8], (const float*)d_in[10],
      (const float*)d_in[15], (const float*)d_in[17], (const float*)d_in[19], ws);
  k_h0     <<<dim3(2048), dim3(256), 0, stream>>>(h0, ws);

  for(int t=0; t<TT; ++t){
    kA    <<<dim3(1024), dim3(256), 0, stream>>>(ws, x, mask, fsW, fsb, lib, gng, gnb, out, t);
    kB    <<<dim3(1024), dim3(256), 0, stream>>>(ws, x, mask, gcb, lob, prelu, roW, rob, out, t);
    k_prop<<<dim3(1024), dim3(256), 0, stream>>>(ws, O_XH, O_XH, O_Z1F, O_Z1B);
    kD    <<<dim3(1024), dim3(512), 0, stream>>>(ws, fb, ub);
    k_prop<<<dim3(1024), dim3(256), 0, stream>>>(ws, O_XC, O_XC, O_Z1F, O_Z1B);
    kF    <<<dim3(1024), dim3(512), 0, stream>>>(ws, cb);
  }
  k_final<<<dim3(1024), dim3(256), 0, stream>>>(ws, gng, gnb);

  k_transpose<<<dim3(2048), dim3(256), 0, stream>>>(ws, out, O_RST, OFF_REPR, 128);
  k_transpose<<<dim3(1024), dim3(256), 0, stream>>>(ws, out, O_SST, OFF_ST, 64);
}